// Round 3
// baseline (221.113 us; speedup 1.0000x reference)
//
#include <hip/hip_runtime.h>

// DiagonalSSM: B=4, T=4096, D=1024, N=256
//   Z[:, :256]  = sigmoid(u @ Wl^T + bl)   (lambda)
//   Z[:, 256:]  = u @ Wb^T                 (Bu)
//   h_t = lam_t * h_{t-1} + bu_t  (scan over T, per (b,n))
//   y = H @ Wc^T + u * Dp
//
// R1: workspace shrunk 77.5MB -> 41.9MB (R0 post-timing divergence = OOB ws
// writes corrupting pristine input copies). u_bf eliminated: GEMM1 reg-stages
// A (f32 global -> cvt -> bf16 ds_write); GEMM2 keeps global_load_lds.
// R2: FIX scan_phase2 grid 1 -> 4 blocks (B*N=1024 threads). R1 ran only 256
// chains; b=1..3 read poisoned carries -> absmax 1.44.

typedef __bf16 bf16_t;
typedef __attribute__((ext_vector_type(8))) __bf16 bf16x8;
typedef __attribute__((ext_vector_type(4))) __bf16 bf16x4;
typedef __attribute__((ext_vector_type(4))) float f32x4;

#define B_  4
#define T_  4096
#define D_  1024
#define N_  256
#define BT  (B_ * T_)          // 16384
#define NCHUNK 32
#define CHLEN  (T_ / NCHUNK)   // 128

#define GLOAD_LDS16(g, l) __builtin_amdgcn_global_load_lds(              \
    (__attribute__((address_space(1))) void*)(g),                        \
    (__attribute__((address_space(3))) void*)(l), 16, 0, 0)

// ---------------- weight converts ----------------
__global__ void cvt_f32_bf16(const float* __restrict__ in,
                             bf16_t* __restrict__ out, int n4) {
  int i = blockIdx.x * 256 + threadIdx.x;
  if (i >= n4) return;
  float4 v = ((const float4*)in)[i];
  bf16x4 o = {(__bf16)v.x, (__bf16)v.y, (__bf16)v.z, (__bf16)v.w};
  ((bf16x4*)out)[i] = o;
}

// build Wcomb[512][1024] = [Wl ; Wb] in bf16
__global__ void cvt_wcomb(const float* __restrict__ Wl,
                          const float* __restrict__ Wb,
                          bf16_t* __restrict__ out) {
  int i = blockIdx.x * 256 + threadIdx.x;  // over 512*1024/4 = 131072
  int e = i * 4;
  int j = e >> 10;          // row 0..511
  int d = e & 1023;
  const float* src = (j < 256) ? (Wl + (size_t)j * D_ + d)
                               : (Wb + (size_t)(j - 256) * D_ + d);
  float4 v = *(const float4*)src;
  bf16x4 o = {(__bf16)v.x, (__bf16)v.y, (__bf16)v.z, (__bf16)v.w};
  ((bf16x4*)out)[i] = o;
}

// ---------------- GEMM1: Z[M,512] = cvt_bf16(u[M,K]) @ Wcomb^T ------------
// A is f32 in global; reg-staged (dwordx4 -> cvt -> ds_write_b64).
// B (bf16) staged via global_load_lds. 128x128 tile, BK=64, 4 waves (2x2).
__global__ __launch_bounds__(256)
void gemm1_kernel(const float* __restrict__ A, const bf16_t* __restrict__ Bm,
                  float* __restrict__ C, int M, int N, int K,
                  const float* __restrict__ bl) {
  __shared__ bf16_t lA[128 * 64];
  __shared__ bf16_t lB[128 * 64];
  const int wid  = threadIdx.x >> 6;
  const int lane = threadIdx.x & 63;
  const int brow = blockIdx.x;
  const int bcol = blockIdx.y;
  const int r16 = lane & 15;
  const int kq  = lane >> 4;
  const int wr = wid >> 1, wc = wid & 1;

  f32x4 acc[4][4] = {};

  // A staging (f32): wave wid covers rows wid*32..wid*32+31.
  // lane: row = lane>>4 (0..3), col = (lane&15)*4; 8 issues stride 4 rows.
  const int ar = lane >> 4;
  const int ac = (lane & 15) * 4;
  const float* gA = A + (size_t)(brow * 128 + wid * 32 + ar) * K + ac;
  bf16_t* lAw = &lA[(wid * 32 + ar) * 64 + ac];

  // B staging (bf16, global_load_lds): wave covers 8 rows/issue, 4 issues.
  const int srow = wid * 8 + (lane >> 3);
  const int scol = (lane & 7) * 8;
  const bf16_t* gB = Bm + (size_t)(bcol * 128 + srow) * K + scol;
  bf16_t* lBd = &lB[(wid * 8) * 64];

  for (int k0 = 0; k0 < K; k0 += 64) {
    float4 va[8];
#pragma unroll
    for (int i = 0; i < 8; ++i)
      va[i] = *(const float4*)(gA + (size_t)(i * 4) * K + k0);
#pragma unroll
    for (int i = 0; i < 4; ++i)
      GLOAD_LDS16(gB + (size_t)(i * 32) * K + k0, lBd + i * 32 * 64);
#pragma unroll
    for (int i = 0; i < 8; ++i) {
      bf16x4 o = {(__bf16)va[i].x, (__bf16)va[i].y,
                  (__bf16)va[i].z, (__bf16)va[i].w};
      *(bf16x4*)(lAw + i * 4 * 64) = o;
    }
    __syncthreads();
#pragma unroll
    for (int kk = 0; kk < 2; ++kk) {
      bf16x8 af[4], bfr[4];
#pragma unroll
      for (int m = 0; m < 4; ++m)
        af[m] = *(const bf16x8*)&lA[(wr * 64 + m * 16 + r16) * 64 + kk * 32 + kq * 8];
#pragma unroll
      for (int n = 0; n < 4; ++n)
        bfr[n] = *(const bf16x8*)&lB[(wc * 64 + n * 16 + r16) * 64 + kk * 32 + kq * 8];
#pragma unroll
      for (int m = 0; m < 4; ++m)
#pragma unroll
        for (int n = 0; n < 4; ++n)
          acc[m][n] = __builtin_amdgcn_mfma_f32_16x16x32_bf16(af[m], bfr[n], acc[m][n], 0, 0, 0);
    }
    __syncthreads();
  }

  // epilogue: C/D layout col = lane&15, row = (lane>>4)*4 + j  [m89]
#pragma unroll
  for (int m = 0; m < 4; ++m) {
#pragma unroll
    for (int n = 0; n < 4; ++n) {
      int row0 = brow * 128 + wr * 64 + m * 16 + kq * 4;
      int col  = bcol * 128 + wc * 64 + n * 16 + r16;
#pragma unroll
      for (int j = 0; j < 4; ++j) {
        float v = acc[m][n][j];
        int row = row0 + j;
        if (col < 256) v = 1.0f / (1.0f + __expf(-(v + bl[col])));
        C[(size_t)row * N + col] = v;
      }
    }
  }
}

// ---------------- GEMM2: y[M,1024] = H[M,256] @ Wc^T + u*Dp ----------------
__global__ __launch_bounds__(256)
void gemm2_kernel(const bf16_t* __restrict__ A, const bf16_t* __restrict__ Bm,
                  float* __restrict__ C, int M, int N, int K,
                  const float* __restrict__ u, const float* __restrict__ Dp) {
  __shared__ bf16_t lA[128 * 64];
  __shared__ bf16_t lB[128 * 64];
  const int wid  = threadIdx.x >> 6;
  const int lane = threadIdx.x & 63;
  const int brow = blockIdx.x;
  const int bcol = blockIdx.y;
  const int r16 = lane & 15;
  const int kq  = lane >> 4;
  const int wr = wid >> 1, wc = wid & 1;

  f32x4 acc[4][4] = {};

  const int srow = wid * 8 + (lane >> 3);
  const int scol = (lane & 7) * 8;
  const bf16_t* gA = A + (size_t)(brow * 128 + srow) * K + scol;
  const bf16_t* gB = Bm + (size_t)(bcol * 128 + srow) * K + scol;
  bf16_t* lAd = &lA[(wid * 8) * 64];
  bf16_t* lBd = &lB[(wid * 8) * 64];

  for (int k0 = 0; k0 < K; k0 += 64) {
#pragma unroll
    for (int i = 0; i < 4; ++i) {
      GLOAD_LDS16(gA + (size_t)(i * 32) * K + k0, lAd + i * 32 * 64);
      GLOAD_LDS16(gB + (size_t)(i * 32) * K + k0, lBd + i * 32 * 64);
    }
    __syncthreads();
#pragma unroll
    for (int kk = 0; kk < 2; ++kk) {
      bf16x8 af[4], bfr[4];
#pragma unroll
      for (int m = 0; m < 4; ++m)
        af[m] = *(const bf16x8*)&lA[(wr * 64 + m * 16 + r16) * 64 + kk * 32 + kq * 8];
#pragma unroll
      for (int n = 0; n < 4; ++n)
        bfr[n] = *(const bf16x8*)&lB[(wc * 64 + n * 16 + r16) * 64 + kk * 32 + kq * 8];
#pragma unroll
      for (int m = 0; m < 4; ++m)
#pragma unroll
        for (int n = 0; n < 4; ++n)
          acc[m][n] = __builtin_amdgcn_mfma_f32_16x16x32_bf16(af[m], bfr[n], acc[m][n], 0, 0, 0);
    }
    __syncthreads();
  }

#pragma unroll
  for (int m = 0; m < 4; ++m) {
#pragma unroll
    for (int n = 0; n < 4; ++n) {
      int row0 = brow * 128 + wr * 64 + m * 16 + kq * 4;
      int col  = bcol * 128 + wc * 64 + n * 16 + r16;
#pragma unroll
      for (int j = 0; j < 4; ++j) {
        int row = row0 + j;
        float v = acc[m][n][j] + Dp[col] * u[(size_t)row * N + col];
        C[(size_t)row * N + col] = v;
      }
    }
  }
}

// ---------------- scan (3-phase chunked) ----------------
// Z row layout: [lam(256) | bu(256)], row index = b*T_ + t
__global__ void scan_phase1(const float* __restrict__ Z,
                            float* __restrict__ wsA, float* __restrict__ wsB) {
  int tid = blockIdx.x * 256 + threadIdx.x;  // 32768 = B*NCHUNK*N
  int n = tid & 255;
  int chunk = (tid >> 8) & 31;
  int b = tid >> 13;
  const float* zl = Z + ((size_t)(b * T_ + chunk * CHLEN)) * 512 + n;
  float A = 1.f, h = 0.f;
#pragma unroll 4
  for (int t = 0; t < CHLEN; ++t) {
    float lam = zl[0];
    float bu  = zl[256];
    A *= lam;
    h = fmaf(lam, h, bu);
    zl += 512;
  }
  wsA[tid] = A;
  wsB[tid] = h;
}

__global__ void scan_phase2(const float* __restrict__ wsA,
                            const float* __restrict__ wsB,
                            float* __restrict__ carry) {
  int tid = blockIdx.x * 256 + threadIdx.x;  // 1024 = B*N
  int n = tid & 255;
  int b = tid >> 8;
  float h = 0.f;
#pragma unroll
  for (int c = 0; c < NCHUNK; ++c) {
    int idx = (b * NCHUNK + c) * 256 + n;
    carry[idx] = h;
    h = fmaf(wsA[idx], h, wsB[idx]);
  }
}

__global__ void scan_phase3(const float* __restrict__ Z,
                            const float* __restrict__ carry,
                            bf16_t* __restrict__ H) {
  int tid = blockIdx.x * 256 + threadIdx.x;
  int n = tid & 255;
  int chunk = (tid >> 8) & 31;
  int b = tid >> 13;
  const float* zl = Z + ((size_t)(b * T_ + chunk * CHLEN)) * 512 + n;
  bf16_t* ho = H + ((size_t)(b * T_ + chunk * CHLEN)) * 256 + n;
  float h = carry[tid];
#pragma unroll 4
  for (int t = 0; t < CHLEN; ++t) {
    float lam = zl[0];
    float bu  = zl[256];
    h = fmaf(lam, h, bu);
    *ho = (__bf16)h;
    zl += 512;
    ho += 256;
  }
}

// ---------------- launch ----------------
extern "C" void kernel_launch(void* const* d_in, const int* in_sizes, int n_in,
                              void* d_out, int out_size, void* d_ws, size_t ws_size,
                              hipStream_t stream) {
  const float* u  = (const float*)d_in[0];
  const float* Wl = (const float*)d_in[1];
  const float* bl = (const float*)d_in[2];
  const float* Wb = (const float*)d_in[3];
  const float* Wc = (const float*)d_in[4];
  const float* Dp = (const float*)d_in[5];
  float* y = (float*)d_out;

  // compact workspace layout: 43,909,120 B total (~41.9 MB)
  char* ws = (char*)d_ws;
  float*  Z     = (float*)(ws + 0);           // 16384*512 f32  = 33554432 B
  bf16_t* H     = (bf16_t*)(ws + 33554432);   // 16384*256 bf16 =  8388608 B
  bf16_t* Wcomb = (bf16_t*)(ws + 41943040);   // 512*1024 bf16  =  1048576 B
  bf16_t* Wc_bf = (bf16_t*)(ws + 42991616);   // 1024*256 bf16  =   524288 B
  float*  wsA   = (float*)(ws + 43515904);    // 32768 f32      =   131072 B
  float*  wsB   = (float*)(ws + 43646976);    // 32768 f32
  float*  carry = (float*)(ws + 43778048);    // 32768 f32  (end 43909120)

  // weight converts
  cvt_wcomb<<<(512 * D_ / 4) / 256, 256, 0, stream>>>(Wl, Wb, Wcomb);
  cvt_f32_bf16<<<(D_ * N_ / 4) / 256, 256, 0, stream>>>(Wc, Wc_bf, D_ * N_ / 4);

  // GEMM1: Z[16384,512] = bf16(u) @ Wcomb^T  (sigmoid+bias on first 256 cols)
  dim3 g1(BT / 128, 512 / 128);
  gemm1_kernel<<<g1, 256, 0, stream>>>(u, Wcomb, Z, BT, 512, D_, bl);

  // scan
  scan_phase1<<<(B_ * NCHUNK * N_) / 256, 256, 0, stream>>>(Z, wsA, wsB);
  scan_phase2<<<(B_ * N_) / 256, 256, 0, stream>>>(wsA, wsB, carry);
  scan_phase3<<<(B_ * NCHUNK * N_) / 256, 256, 0, stream>>>(Z, carry, H);

  // GEMM2: y[16384,1024] = H @ Wc^T + u*Dp
  dim3 g2(BT / 128, D_ / 128);
  gemm2_kernel<<<g2, 256, 0, stream>>>(H, Wc_bf, y, BT, D_, N_, u, Dp);
}

// Round 5
// 210.814 us; speedup vs baseline: 1.0489x; 1.0489x over previous
//
#include <hip/hip_runtime.h>

// DiagonalSSM: B=4, T=4096, D=1024, N=256
//   Z[:, :256]  = sigmoid(u @ Wl^T + bl)   (lambda)
//   Z[:, 256:]  = u @ Wb^T                 (Bu)
//   h_t = lam_t * h_{t-1} + bu_t  (scan over T, per (b,n))
//   y = H @ Wc^T + u * Dp
//
// R3 passed @221us; gemm1 = 66us, latency-bound (260 TF, 2 blocks/CU, serial
// staging). R4: 2-phase double-buffered pipeline in both GEMMs (prefetch
// next K-tile before computing current; ds_write after MFMA; 1 barrier/iter),
// XCD-aware swizzle in gemm1, scan NCHUNK 32->64.
// R5: fix stale 6-arg gemm2 call (compile error only).

typedef __bf16 bf16_t;
typedef __attribute__((ext_vector_type(8))) __bf16 bf16x8;
typedef __attribute__((ext_vector_type(4))) __bf16 bf16x4;
typedef __attribute__((ext_vector_type(4))) float f32x4;

#define B_  4
#define T_  4096
#define D_  1024
#define N_  256
#define BT  (B_ * T_)          // 16384
#define NCHUNK 64
#define CHLEN  (T_ / NCHUNK)   // 64

#define GLOAD_LDS16(g, l) __builtin_amdgcn_global_load_lds(              \
    (__attribute__((address_space(1))) void*)(g),                        \
    (__attribute__((address_space(3))) void*)(l), 16, 0, 0)

// ---------------- weight converts ----------------
__global__ void cvt_f32_bf16(const float* __restrict__ in,
                             bf16_t* __restrict__ out, int n4) {
  int i = blockIdx.x * 256 + threadIdx.x;
  if (i >= n4) return;
  float4 v = ((const float4*)in)[i];
  bf16x4 o = {(__bf16)v.x, (__bf16)v.y, (__bf16)v.z, (__bf16)v.w};
  ((bf16x4*)out)[i] = o;
}

// build Wcomb[512][1024] = [Wl ; Wb] in bf16
__global__ void cvt_wcomb(const float* __restrict__ Wl,
                          const float* __restrict__ Wb,
                          bf16_t* __restrict__ out) {
  int i = blockIdx.x * 256 + threadIdx.x;  // over 512*1024/4 = 131072
  int e = i * 4;
  int j = e >> 10;          // row 0..511
  int d = e & 1023;
  const float* src = (j < 256) ? (Wl + (size_t)j * D_ + d)
                               : (Wb + (size_t)(j - 256) * D_ + d);
  float4 v = *(const float4*)src;
  bf16x4 o = {(__bf16)v.x, (__bf16)v.y, (__bf16)v.z, (__bf16)v.w};
  ((bf16x4*)out)[i] = o;
}

// shared MFMA inner tile: 4x4 fragments, BK=64 (2x kk)
__device__ __forceinline__ void mfma_tile(const bf16_t* bufA, const bf16_t* bufB,
                                          int wr, int wc, int r16, int kq,
                                          f32x4 (&acc)[4][4]) {
#pragma unroll
  for (int kk = 0; kk < 2; ++kk) {
    bf16x8 af[4], bfr[4];
#pragma unroll
    for (int m = 0; m < 4; ++m)
      af[m] = *(const bf16x8*)&bufA[(wr * 64 + m * 16 + r16) * 64 + kk * 32 + kq * 8];
#pragma unroll
    for (int n = 0; n < 4; ++n)
      bfr[n] = *(const bf16x8*)&bufB[(wc * 64 + n * 16 + r16) * 64 + kk * 32 + kq * 8];
#pragma unroll
    for (int m = 0; m < 4; ++m)
#pragma unroll
      for (int n = 0; n < 4; ++n)
        acc[m][n] = __builtin_amdgcn_mfma_f32_16x16x32_bf16(af[m], bfr[n], acc[m][n], 0, 0, 0);
  }
}

// ---------------- GEMM1: Z[16384,512] = bf16(u) @ Wcomb^T ------------------
// A f32 reg-staged (issue-early, ds_write-late); B via global_load_lds.
// 2-phase double-buffered; XCD swizzle groups the 4 bcol-blocks of one brow.
__global__ __launch_bounds__(256)
void gemm1_kernel(const float* __restrict__ A, const bf16_t* __restrict__ Bm,
                  float* __restrict__ C, const float* __restrict__ bl) {
  __shared__ bf16_t lA[2][128 * 64];
  __shared__ bf16_t lB[2][128 * 64];
  const int wid  = threadIdx.x >> 6;
  const int lane = threadIdx.x & 63;
  // XCD swizzle: hw round-robins blockIdx%8 across XCDs. Give XCD x a
  // contiguous brow range with bcol fastest: work = (hw&7)*64 + (hw>>3).
  const int work = (blockIdx.x & 7) * 64 + (blockIdx.x >> 3);  // grid=512
  const int brow = work >> 2;
  const int bcol = work & 3;
  const int r16 = lane & 15;
  const int kq  = lane >> 4;
  const int wr = wid >> 1, wc = wid & 1;

  f32x4 acc[4][4] = {};

  // A staging (f32): lane row = lane>>4 (0..3), col = (lane&15)*4; 8 issues.
  const int ar = lane >> 4;
  const int ac = (lane & 15) * 4;
  const float* gA = A + (size_t)(brow * 128 + wid * 32 + ar) * D_ + ac;
  bf16_t* lAw[2] = {&lA[0][(wid * 32 + ar) * 64 + ac],
                    &lA[1][(wid * 32 + ar) * 64 + ac]};

  // B staging (bf16, global_load_lds): 8 rows/issue/wave, 4 issues.
  const bf16_t* gB = Bm + (size_t)(bcol * 128 + wid * 8 + (lane >> 3)) * D_ + (lane & 7) * 8;

  // prologue: stage k0=0 into buf 0
  {
    float4 va[8];
#pragma unroll
    for (int i = 0; i < 8; ++i)
      va[i] = *(const float4*)(gA + (size_t)(i * 4) * D_);
#pragma unroll
    for (int i = 0; i < 4; ++i)
      GLOAD_LDS16(gB + (size_t)(i * 32) * D_, &lB[0][(wid * 8 + i * 32) * 64]);
#pragma unroll
    for (int i = 0; i < 8; ++i) {
      bf16x4 o = {(__bf16)va[i].x, (__bf16)va[i].y,
                  (__bf16)va[i].z, (__bf16)va[i].w};
      *(bf16x4*)(lAw[0] + i * 4 * 64) = o;
    }
    __syncthreads();
  }

  int cur = 0;
#pragma unroll 1
  for (int k0 = 0; k0 < D_ - 64; k0 += 64) {
    // prefetch k0+64: issue loads BEFORE compute
    float4 va[8];
#pragma unroll
    for (int i = 0; i < 8; ++i)
      va[i] = *(const float4*)(gA + (size_t)(i * 4) * D_ + k0 + 64);
#pragma unroll
    for (int i = 0; i < 4; ++i)
      GLOAD_LDS16(gB + (size_t)(i * 32) * D_ + k0 + 64,
                  &lB[cur ^ 1][(wid * 8 + i * 32) * 64]);
    // compute current tile
    mfma_tile(lA[cur], lB[cur], wr, wc, r16, kq, acc);
    // write-late: cvt + ds_write into the other buffer
#pragma unroll
    for (int i = 0; i < 8; ++i) {
      bf16x4 o = {(__bf16)va[i].x, (__bf16)va[i].y,
                  (__bf16)va[i].z, (__bf16)va[i].w};
      *(bf16x4*)(lAw[cur ^ 1] + i * 4 * 64) = o;
    }
    __syncthreads();   // drains lgkm (ds_writes) + vmcnt (gload_lds)
    cur ^= 1;
  }
  mfma_tile(lA[cur], lB[cur], wr, wc, r16, kq, acc);

  // epilogue: C/D layout col = lane&15, row = (lane>>4)*4 + j  [m89]
#pragma unroll
  for (int m = 0; m < 4; ++m) {
#pragma unroll
    for (int n = 0; n < 4; ++n) {
      int row0 = brow * 128 + wr * 64 + m * 16 + kq * 4;
      int col  = bcol * 128 + wc * 64 + n * 16 + r16;
#pragma unroll
      for (int j = 0; j < 4; ++j) {
        float v = acc[m][n][j];
        int row = row0 + j;
        if (col < 256) v = 1.0f / (1.0f + __expf(-(v + bl[col])));
        C[(size_t)row * 512 + col] = v;
      }
    }
  }
}

// ---------------- GEMM2: y[16384,1024] = H @ Wc^T + u*Dp -------------------
// Both operands via global_load_lds; 2-phase double-buffered. K=256 (4 steps).
__global__ __launch_bounds__(256)
void gemm2_kernel(const bf16_t* __restrict__ A, const bf16_t* __restrict__ Bm,
                  float* __restrict__ C,
                  const float* __restrict__ u, const float* __restrict__ Dp) {
  __shared__ bf16_t lA[2][128 * 64];
  __shared__ bf16_t lB[2][128 * 64];
  const int wid  = threadIdx.x >> 6;
  const int lane = threadIdx.x & 63;
  const int brow = blockIdx.x;
  const int bcol = blockIdx.y;
  const int r16 = lane & 15;
  const int kq  = lane >> 4;
  const int wr = wid >> 1, wc = wid & 1;

  f32x4 acc[4][4] = {};

  const bf16_t* gA = A + (size_t)(brow * 128 + wid * 8 + (lane >> 3)) * N_ + (lane & 7) * 8;
  const bf16_t* gB = Bm + (size_t)(bcol * 128 + wid * 8 + (lane >> 3)) * N_ + (lane & 7) * 8;

  // prologue
  {
#pragma unroll
    for (int i = 0; i < 4; ++i) {
      GLOAD_LDS16(gA + (size_t)(i * 32) * N_, &lA[0][(wid * 8 + i * 32) * 64]);
      GLOAD_LDS16(gB + (size_t)(i * 32) * N_, &lB[0][(wid * 8 + i * 32) * 64]);
    }
    __syncthreads();
  }
  int cur = 0;
#pragma unroll 1
  for (int k0 = 0; k0 < N_ - 64; k0 += 64) {
#pragma unroll
    for (int i = 0; i < 4; ++i) {
      GLOAD_LDS16(gA + (size_t)(i * 32) * N_ + k0 + 64,
                  &lA[cur ^ 1][(wid * 8 + i * 32) * 64]);
      GLOAD_LDS16(gB + (size_t)(i * 32) * N_ + k0 + 64,
                  &lB[cur ^ 1][(wid * 8 + i * 32) * 64]);
    }
    mfma_tile(lA[cur], lB[cur], wr, wc, r16, kq, acc);
    __syncthreads();
    cur ^= 1;
  }
  mfma_tile(lA[cur], lB[cur], wr, wc, r16, kq, acc);

#pragma unroll
  for (int m = 0; m < 4; ++m) {
#pragma unroll
    for (int n = 0; n < 4; ++n) {
      int row0 = brow * 128 + wr * 64 + m * 16 + kq * 4;
      int col  = bcol * 128 + wc * 64 + n * 16 + r16;
#pragma unroll
      for (int j = 0; j < 4; ++j) {
        int row = row0 + j;
        float v = acc[m][n][j] + Dp[col] * u[(size_t)row * D_ + col];
        C[(size_t)row * D_ + col] = v;
      }
    }
  }
}

// ---------------- scan (3-phase chunked, NCHUNK=64) ----------------
// Z row layout: [lam(256) | bu(256)], row index = b*T_ + t
__global__ void scan_phase1(const float* __restrict__ Z,
                            float* __restrict__ wsA, float* __restrict__ wsB) {
  int tid = blockIdx.x * 256 + threadIdx.x;  // 65536 = B*NCHUNK*N
  int n = tid & 255;
  int chunk = (tid >> 8) & (NCHUNK - 1);
  int b = tid >> 14;
  const float* zl = Z + ((size_t)(b * T_ + chunk * CHLEN)) * 512 + n;
  float A = 1.f, h = 0.f;
#pragma unroll 8
  for (int t = 0; t < CHLEN; ++t) {
    float lam = zl[0];
    float bu  = zl[256];
    A *= lam;
    h = fmaf(lam, h, bu);
    zl += 512;
  }
  wsA[tid] = A;
  wsB[tid] = h;
}

__global__ void scan_phase2(const float* __restrict__ wsA,
                            const float* __restrict__ wsB,
                            float* __restrict__ carry) {
  int tid = blockIdx.x * 256 + threadIdx.x;  // 1024 = B*N
  int n = tid & 255;
  int b = tid >> 8;
  float h = 0.f;
#pragma unroll
  for (int c = 0; c < NCHUNK; ++c) {
    int idx = (b * NCHUNK + c) * 256 + n;
    carry[idx] = h;
    h = fmaf(wsA[idx], h, wsB[idx]);
  }
}

__global__ void scan_phase3(const float* __restrict__ Z,
                            const float* __restrict__ carry,
                            bf16_t* __restrict__ H) {
  int tid = blockIdx.x * 256 + threadIdx.x;
  int n = tid & 255;
  int chunk = (tid >> 8) & (NCHUNK - 1);
  int b = tid >> 14;
  const float* zl = Z + ((size_t)(b * T_ + chunk * CHLEN)) * 512 + n;
  bf16_t* ho = H + ((size_t)(b * T_ + chunk * CHLEN)) * 256 + n;
  float h = carry[tid];
#pragma unroll 8
  for (int t = 0; t < CHLEN; ++t) {
    float lam = zl[0];
    float bu  = zl[256];
    h = fmaf(lam, h, bu);
    *ho = (__bf16)h;
    zl += 512;
    ho += 256;
  }
}

// ---------------- launch ----------------
extern "C" void kernel_launch(void* const* d_in, const int* in_sizes, int n_in,
                              void* d_out, int out_size, void* d_ws, size_t ws_size,
                              hipStream_t stream) {
  const float* u  = (const float*)d_in[0];
  const float* Wl = (const float*)d_in[1];
  const float* bl = (const float*)d_in[2];
  const float* Wb = (const float*)d_in[3];
  const float* Wc = (const float*)d_in[4];
  const float* Dp = (const float*)d_in[5];
  float* y = (float*)d_out;

  // compact workspace layout: ~44.3 MB total
  char* ws = (char*)d_ws;
  float*  Z     = (float*)(ws + 0);           // 16384*512 f32  = 33554432 B
  bf16_t* H     = (bf16_t*)(ws + 33554432);   // 16384*256 bf16 =  8388608 B
  bf16_t* Wcomb = (bf16_t*)(ws + 41943040);   // 512*1024 bf16  =  1048576 B
  bf16_t* Wc_bf = (bf16_t*)(ws + 42991616);   // 1024*256 bf16  =   524288 B
  float*  wsA   = (float*)(ws + 43515904);    // 65536 f32      =   262144 B
  float*  wsB   = (float*)(ws + 43778048);    // 65536 f32
  float*  carry = (float*)(ws + 44040192);    // 65536 f32  (end 44302336)

  // weight converts
  cvt_wcomb<<<(512 * D_ / 4) / 256, 256, 0, stream>>>(Wl, Wb, Wcomb);
  cvt_f32_bf16<<<(D_ * N_ / 4) / 256, 256, 0, stream>>>(Wc, Wc_bf, D_ * N_ / 4);

  // GEMM1: Z[16384,512] = bf16(u) @ Wcomb^T  (sigmoid+bias on first 256 cols)
  gemm1_kernel<<<512, 256, 0, stream>>>(u, Wcomb, Z, bl);

  // scan
  scan_phase1<<<(B_ * NCHUNK * N_) / 256, 256, 0, stream>>>(Z, wsA, wsB);
  scan_phase2<<<(B_ * N_) / 256, 256, 0, stream>>>(wsA, wsB, carry);
  scan_phase3<<<(B_ * NCHUNK * N_) / 256, 256, 0, stream>>>(Z, carry, H);

  // GEMM2: y[16384,1024] = H @ Wc^T + u*Dp
  dim3 g2(BT / 128, D_ / 128);
  gemm2_kernel<<<g2, 256, 0, stream>>>(H, Wc_bf, y, u, Dp);
}

// Round 8
// 200.636 us; speedup vs baseline: 1.1021x; 1.0507x over previous
//
#include <hip/hip_runtime.h>

// DiagonalSSM: B=4, T=4096, D=1024, N=256
//   Z[:, :256]  = sigmoid(u @ Wl^T + bl)   (lambda)
//   Z[:, 256:]  = u @ Wb^T                 (Bu)
//   h_t = lam_t * h_{t-1} + bu_t  (scan over T, per (b,n))
//   y = H @ Wc^T + u * Dp
//
// R5 @210us: gemm1 67us latency-bound (Occ 14%, MfmaUtil 9%, 6.3M LDS bank
// conflicts). R6: 8 waves/block (512 thr, 4 waves/SIMD) + T2 XOR swizzle on
// LDS tiles (read ^((r16&7)<<3); A via swizzled ds_write; B via pre-swizzled
// GLOBAL source col since global_load_lds dest is linear — rule 21).
// R7/R8: identical resubmits (R6+R7 benches were GPU-acquisition timeouts).

typedef __bf16 bf16_t;
typedef __attribute__((ext_vector_type(8))) __bf16 bf16x8;
typedef __attribute__((ext_vector_type(4))) __bf16 bf16x4;
typedef __attribute__((ext_vector_type(4))) float f32x4;

#define B_  4
#define T_  4096
#define D_  1024
#define N_  256
#define BT  (B_ * T_)          // 16384
#define NCHUNK 64
#define CHLEN  (T_ / NCHUNK)   // 64

#define GLOAD_LDS16(g, l) __builtin_amdgcn_global_load_lds(              \
    (__attribute__((address_space(1))) void*)(g),                        \
    (__attribute__((address_space(3))) void*)(l), 16, 0, 0)

// ---------------- weight converts ----------------
__global__ void cvt_f32_bf16(const float* __restrict__ in,
                             bf16_t* __restrict__ out, int n4) {
  int i = blockIdx.x * 256 + threadIdx.x;
  if (i >= n4) return;
  float4 v = ((const float4*)in)[i];
  bf16x4 o = {(__bf16)v.x, (__bf16)v.y, (__bf16)v.z, (__bf16)v.w};
  ((bf16x4*)out)[i] = o;
}

// build Wcomb[512][1024] = [Wl ; Wb] in bf16
__global__ void cvt_wcomb(const float* __restrict__ Wl,
                          const float* __restrict__ Wb,
                          bf16_t* __restrict__ out) {
  int i = blockIdx.x * 256 + threadIdx.x;  // over 512*1024/4 = 131072
  int e = i * 4;
  int j = e >> 10;          // row 0..511
  int d = e & 1023;
  const float* src = (j < 256) ? (Wl + (size_t)j * D_ + d)
                               : (Wb + (size_t)(j - 256) * D_ + d);
  float4 v = *(const float4*)src;
  bf16x4 o = {(__bf16)v.x, (__bf16)v.y, (__bf16)v.z, (__bf16)v.w};
  ((bf16x4*)out)[i] = o;
}

// MFMA inner tile, 8-wave version: wave tile 64x32 (4m x 2n frags), BK=64.
// LDS tiles are XOR-swizzled: elem idx ^= (row&7)<<3.
__device__ __forceinline__ void mfma_tile8(const bf16_t* bufA, const bf16_t* bufB,
                                           int wr, int wc, int r16, int kq,
                                           f32x4 (&acc)[4][2]) {
  const int sw = (r16 & 7) << 3;
#pragma unroll
  for (int kk = 0; kk < 2; ++kk) {
    bf16x8 af[4], bfr[2];
#pragma unroll
    for (int m = 0; m < 4; ++m) {
      int idx = (wr * 64 + m * 16 + r16) * 64 + kk * 32 + kq * 8;
      af[m] = *(const bf16x8*)&bufA[idx ^ sw];
    }
#pragma unroll
    for (int n = 0; n < 2; ++n) {
      int idx = (wc * 32 + n * 16 + r16) * 64 + kk * 32 + kq * 8;
      bfr[n] = *(const bf16x8*)&bufB[idx ^ sw];
    }
#pragma unroll
    for (int m = 0; m < 4; ++m)
#pragma unroll
      for (int n = 0; n < 2; ++n)
        acc[m][n] = __builtin_amdgcn_mfma_f32_16x16x32_bf16(af[m], bfr[n], acc[m][n], 0, 0, 0);
  }
}

// ---------------- GEMM1: Z[16384,512] = bf16(u) @ Wcomb^T ------------------
// 8 waves, 128x128 tile, dbuf. A f32 reg-staged w/ swizzled ds_write;
// B via global_load_lds w/ pre-swizzled global col. XCD swizzle on blockIdx.
__global__ __launch_bounds__(512, 4)
void gemm1_kernel(const float* __restrict__ A, const bf16_t* __restrict__ Bm,
                  float* __restrict__ C, const float* __restrict__ bl) {
  __shared__ bf16_t lA[2][128 * 64];
  __shared__ bf16_t lB[2][128 * 64];
  const int wid  = threadIdx.x >> 6;   // 0..7
  const int lane = threadIdx.x & 63;
  const int work = (blockIdx.x & 7) * 64 + (blockIdx.x >> 3);  // grid=512
  const int brow = work >> 2;
  const int bcol = work & 3;
  const int r16 = lane & 15;
  const int kq  = lane >> 4;
  const int wr = wid >> 2, wc = wid & 3;

  f32x4 acc[4][2] = {};

  // A staging (f32): wave covers rows wid*16..+15; 4 issues of 4 rows.
  const int ar = lane >> 4;            // 0..3
  const int ac = (lane & 15) * 4;
  const float* gA = A + (size_t)(brow * 128 + wid * 16 + ar) * D_ + ac;
  const int aw_base = (wid * 16 + ar) * 64 + ac;   // elem idx, issue i adds i*4*64

  // B staging (gload_lds): wave covers rows wid*16..+15; 2 issues of 8 rows.
  // Pre-swizzled global col so linear LDS dest yields swizzled layout.
  const bf16_t* gB = Bm + (size_t)(bcol * 128 + wid * 16 + (lane >> 3)) * D_
                        + (size_t)(((lane & 7) ^ (lane >> 3)) * 8);

  // prologue: stage k0=0 into buf 0
  {
    float4 va[4];
#pragma unroll
    for (int i = 0; i < 4; ++i)
      va[i] = *(const float4*)(gA + (size_t)(i * 4) * D_);
#pragma unroll
    for (int i = 0; i < 2; ++i)
      GLOAD_LDS16(gB + (size_t)(i * 8) * D_, &lB[0][(wid * 16 + i * 8) * 64]);
#pragma unroll
    for (int i = 0; i < 4; ++i) {
      bf16x4 o = {(__bf16)va[i].x, (__bf16)va[i].y,
                  (__bf16)va[i].z, (__bf16)va[i].w};
      int idx = (aw_base + i * 4 * 64) ^ (((ar + 4 * (i & 1)) & 7) << 3);
      *(bf16x4*)&lA[0][idx] = o;
    }
    __syncthreads();
  }

  int cur = 0;
#pragma unroll 1
  for (int k0 = 0; k0 < D_ - 64; k0 += 64) {
    float4 va[4];
#pragma unroll
    for (int i = 0; i < 4; ++i)
      va[i] = *(const float4*)(gA + (size_t)(i * 4) * D_ + k0 + 64);
#pragma unroll
    for (int i = 0; i < 2; ++i)
      GLOAD_LDS16(gB + (size_t)(i * 8) * D_ + k0 + 64,
                  &lB[cur ^ 1][(wid * 16 + i * 8) * 64]);
    mfma_tile8(lA[cur], lB[cur], wr, wc, r16, kq, acc);
#pragma unroll
    for (int i = 0; i < 4; ++i) {
      bf16x4 o = {(__bf16)va[i].x, (__bf16)va[i].y,
                  (__bf16)va[i].z, (__bf16)va[i].w};
      int idx = (aw_base + i * 4 * 64) ^ (((ar + 4 * (i & 1)) & 7) << 3);
      *(bf16x4*)&lA[cur ^ 1][idx] = o;
    }
    __syncthreads();
    cur ^= 1;
  }
  mfma_tile8(lA[cur], lB[cur], wr, wc, r16, kq, acc);

  // epilogue: C/D layout col = lane&15, row = (lane>>4)*4 + j  [m89]
#pragma unroll
  for (int m = 0; m < 4; ++m) {
#pragma unroll
    for (int n = 0; n < 2; ++n) {
      int row0 = brow * 128 + wr * 64 + m * 16 + kq * 4;
      int col  = bcol * 128 + wc * 32 + n * 16 + r16;
#pragma unroll
      for (int j = 0; j < 4; ++j) {
        float v = acc[m][n][j];
        int row = row0 + j;
        if (col < 256) v = 1.0f / (1.0f + __expf(-(v + bl[col])));
        C[(size_t)row * 512 + col] = v;
      }
    }
  }
}

// ---------------- GEMM2: y[16384,1024] = H @ Wc^T + u*Dp -------------------
// 8 waves, both operands gload_lds w/ pre-swizzled global col, dbuf, K=256.
__global__ __launch_bounds__(512, 4)
void gemm2_kernel(const bf16_t* __restrict__ A, const bf16_t* __restrict__ Bm,
                  float* __restrict__ C,
                  const float* __restrict__ u, const float* __restrict__ Dp) {
  __shared__ bf16_t lA[2][128 * 64];
  __shared__ bf16_t lB[2][128 * 64];
  const int wid  = threadIdx.x >> 6;
  const int lane = threadIdx.x & 63;
  const int brow = blockIdx.x;
  const int bcol = blockIdx.y;
  const int r16 = lane & 15;
  const int kq  = lane >> 4;
  const int wr = wid >> 2, wc = wid & 3;

  f32x4 acc[4][2] = {};

  const size_t scol = ((lane & 7) ^ (lane >> 3)) * 8;
  const bf16_t* gA = A + (size_t)(brow * 128 + wid * 16 + (lane >> 3)) * N_ + scol;
  const bf16_t* gB = Bm + (size_t)(bcol * 128 + wid * 16 + (lane >> 3)) * N_ + scol;

  {
#pragma unroll
    for (int i = 0; i < 2; ++i) {
      GLOAD_LDS16(gA + (size_t)(i * 8) * N_, &lA[0][(wid * 16 + i * 8) * 64]);
      GLOAD_LDS16(gB + (size_t)(i * 8) * N_, &lB[0][(wid * 16 + i * 8) * 64]);
    }
    __syncthreads();
  }
  int cur = 0;
#pragma unroll 1
  for (int k0 = 0; k0 < N_ - 64; k0 += 64) {
#pragma unroll
    for (int i = 0; i < 2; ++i) {
      GLOAD_LDS16(gA + (size_t)(i * 8) * N_ + k0 + 64,
                  &lA[cur ^ 1][(wid * 16 + i * 8) * 64]);
      GLOAD_LDS16(gB + (size_t)(i * 8) * N_ + k0 + 64,
                  &lB[cur ^ 1][(wid * 16 + i * 8) * 64]);
    }
    mfma_tile8(lA[cur], lB[cur], wr, wc, r16, kq, acc);
    __syncthreads();
    cur ^= 1;
  }
  mfma_tile8(lA[cur], lB[cur], wr, wc, r16, kq, acc);

#pragma unroll
  for (int m = 0; m < 4; ++m) {
#pragma unroll
    for (int n = 0; n < 2; ++n) {
      int row0 = brow * 128 + wr * 64 + m * 16 + kq * 4;
      int col  = bcol * 128 + wc * 32 + n * 16 + r16;
#pragma unroll
      for (int j = 0; j < 4; ++j) {
        int row = row0 + j;
        float v = acc[m][n][j] + Dp[col] * u[(size_t)row * D_ + col];
        C[(size_t)row * D_ + col] = v;
      }
    }
  }
}

// ---------------- scan (3-phase chunked, NCHUNK=64) ----------------
// Z row layout: [lam(256) | bu(256)], row index = b*T_ + t
__global__ void scan_phase1(const float* __restrict__ Z,
                            float* __restrict__ wsA, float* __restrict__ wsB) {
  int tid = blockIdx.x * 256 + threadIdx.x;  // 65536 = B*NCHUNK*N
  int n = tid & 255;
  int chunk = (tid >> 8) & (NCHUNK - 1);
  int b = tid >> 14;
  const float* zl = Z + ((size_t)(b * T_ + chunk * CHLEN)) * 512 + n;
  float A = 1.f, h = 0.f;
#pragma unroll 8
  for (int t = 0; t < CHLEN; ++t) {
    float lam = zl[0];
    float bu  = zl[256];
    A *= lam;
    h = fmaf(lam, h, bu);
    zl += 512;
  }
  wsA[tid] = A;
  wsB[tid] = h;
}

__global__ void scan_phase2(const float* __restrict__ wsA,
                            const float* __restrict__ wsB,
                            float* __restrict__ carry) {
  int tid = blockIdx.x * 256 + threadIdx.x;  // 1024 = B*N
  int n = tid & 255;
  int b = tid >> 8;
  float h = 0.f;
#pragma unroll
  for (int c = 0; c < NCHUNK; ++c) {
    int idx = (b * NCHUNK + c) * 256 + n;
    carry[idx] = h;
    h = fmaf(wsA[idx], h, wsB[idx]);
  }
}

__global__ void scan_phase3(const float* __restrict__ Z,
                            const float* __restrict__ carry,
                            bf16_t* __restrict__ H) {
  int tid = blockIdx.x * 256 + threadIdx.x;
  int n = tid & 255;
  int chunk = (tid >> 8) & (NCHUNK - 1);
  int b = tid >> 14;
  const float* zl = Z + ((size_t)(b * T_ + chunk * CHLEN)) * 512 + n;
  bf16_t* ho = H + ((size_t)(b * T_ + chunk * CHLEN)) * 256 + n;
  float h = carry[tid];
#pragma unroll 8
  for (int t = 0; t < CHLEN; ++t) {
    float lam = zl[0];
    float bu  = zl[256];
    h = fmaf(lam, h, bu);
    *ho = (__bf16)h;
    zl += 512;
    ho += 256;
  }
}

// ---------------- launch ----------------
extern "C" void kernel_launch(void* const* d_in, const int* in_sizes, int n_in,
                              void* d_out, int out_size, void* d_ws, size_t ws_size,
                              hipStream_t stream) {
  const float* u  = (const float*)d_in[0];
  const float* Wl = (const float*)d_in[1];
  const float* bl = (const float*)d_in[2];
  const float* Wb = (const float*)d_in[3];
  const float* Wc = (const float*)d_in[4];
  const float* Dp = (const float*)d_in[5];
  float* y = (float*)d_out;

  // compact workspace layout: ~44.3 MB total
  char* ws = (char*)d_ws;
  float*  Z     = (float*)(ws + 0);           // 16384*512 f32  = 33554432 B
  bf16_t* H     = (bf16_t*)(ws + 33554432);   // 16384*256 bf16 =  8388608 B
  bf16_t* Wcomb = (bf16_t*)(ws + 41943040);   // 512*1024 bf16  =  1048576 B
  bf16_t* Wc_bf = (bf16_t*)(ws + 42991616);   // 1024*256 bf16  =   524288 B
  float*  wsA   = (float*)(ws + 43515904);    // 65536 f32      =   262144 B
  float*  wsB   = (float*)(ws + 43778048);    // 65536 f32
  float*  carry = (float*)(ws + 44040192);    // 65536 f32  (end 44302336)

  // weight converts
  cvt_wcomb<<<(512 * D_ / 4) / 256, 256, 0, stream>>>(Wl, Wb, Wcomb);
  cvt_f32_bf16<<<(D_ * N_ / 4) / 256, 256, 0, stream>>>(Wc, Wc_bf, D_ * N_ / 4);

  // GEMM1: Z[16384,512] = bf16(u) @ Wcomb^T  (sigmoid+bias on first 256 cols)
  gemm1_kernel<<<512, 512, 0, stream>>>(u, Wcomb, Z, bl);

  // scan
  scan_phase1<<<(B_ * NCHUNK * N_) / 256, 256, 0, stream>>>(Z, wsA, wsB);
  scan_phase2<<<(B_ * N_) / 256, 256, 0, stream>>>(wsA, wsB, carry);
  scan_phase3<<<(B_ * NCHUNK * N_) / 256, 256, 0, stream>>>(Z, carry, H);

  // GEMM2: y[16384,1024] = H @ Wc^T + u*Dp
  dim3 g2(BT / 128, D_ / 128);
  gemm2_kernel<<<g2, 512, 0, stream>>>(H, Wc_bf, y, u, Dp);
}